// Round 3
// baseline (514.269 us; speedup 1.0000x reference)
//
#include <hip/hip_runtime.h>
#include <hip/hip_bf16.h>
#include <math.h>

#define D_MODEL 1024
#define D_FF    4096
#define N_HEADS 16
#define SEQ     1000
#define BATCH   8
#define M_TOK   (BATCH * SEQ)   // 8000 tokens

typedef __bf16 bf16x8_t __attribute__((ext_vector_type(8)));
typedef short  short8_t __attribute__((ext_vector_type(8)));
typedef float  f32x4_t  __attribute__((ext_vector_type(4)));

__device__ __forceinline__ f32x4_t mfma_bf16(short8_t a, short8_t b, f32x4_t c) {
    return __builtin_amdgcn_mfma_f32_16x16x32_bf16(
        __builtin_bit_cast(bf16x8_t, a), __builtin_bit_cast(bf16x8_t, b), c, 0, 0, 0);
}

// fp32 -> bf16 round-to-nearest-even
__device__ __forceinline__ unsigned short f2bf(float f) {
    union { float f; unsigned u; } x; x.f = f;
    unsigned r = (x.u + 0x7fffu + ((x.u >> 16) & 1u)) >> 16;
    return (unsigned short)r;
}

// fast GELU (tanh form): max abs dev vs exact erf-GELU ~3e-4, below bf16 rounding
__device__ __forceinline__ float gelu_fast(float v) {
    float z = 1.5957691216f * v * fmaf(0.044715f, v * v, 1.0f);
    float e = __expf(-z);                       // v_exp_f32
    return v * __builtin_amdgcn_rcpf(1.0f + e); // v_rcp_f32
}

// async global(16B/lane) -> LDS (wave-uniform base + lane*16)
__device__ __forceinline__ void gload_lds16(const void* g, void* l) {
    __builtin_amdgcn_global_load_lds(
        (const __attribute__((address_space(1))) unsigned int*)g,
        (__attribute__((address_space(3))) unsigned int*)l, 16, 0, 0);
}

// ---------------------------------------------------------------------------
// Prep: all 6 weight transposes (fp32 [K][N] -> bf16 [N][K]) + LN1, one launch.
// ---------------------------------------------------------------------------
__global__ __launch_bounds__(256) void prep_kernel(
    const float* __restrict__ wq, const float* __restrict__ wk,
    const float* __restrict__ wv, const float* __restrict__ wo,
    const float* __restrict__ w1, const float* __restrict__ w2,
    unsigned short* __restrict__ wqt, unsigned short* __restrict__ wkt,
    unsigned short* __restrict__ wvt, unsigned short* __restrict__ wot,
    unsigned short* __restrict__ w1t, unsigned short* __restrict__ w2t,
    const float* __restrict__ x, const float* __restrict__ g1,
    const float* __restrict__ beta1, unsigned short* __restrict__ h1) {
    int id = blockIdx.x;
    __shared__ float tile[32][33];
    __shared__ float red[8];
    if (id >= 12288) {
        // ---- LayerNorm row ----
        int row = id - 12288, tid = threadIdx.x;
        const float4 v = ((const float4*)(x + (size_t)row * D_MODEL))[tid];
        float s  = v.x + v.y + v.z + v.w;
        float s2 = v.x * v.x + v.y * v.y + v.z * v.z + v.w * v.w;
#pragma unroll
        for (int o = 32; o > 0; o >>= 1) { s += __shfl_xor(s, o, 64); s2 += __shfl_xor(s2, o, 64); }
        int wave = tid >> 6, lane = tid & 63;
        if (lane == 0) { red[wave] = s; red[wave + 4] = s2; }
        __syncthreads();
        s  = red[0] + red[1] + red[2] + red[3];
        s2 = red[4] + red[5] + red[6] + red[7];
        float mean = s * (1.0f / D_MODEL);
        float var  = s2 * (1.0f / D_MODEL) - mean * mean;
        float rstd = rsqrtf(var + 1e-5f);
        float4 gg = ((const float4*)g1)[tid];
        float4 bb = ((const float4*)beta1)[tid];
        ushort4 o4;
        o4.x = f2bf((v.x - mean) * rstd * gg.x + bb.x);
        o4.y = f2bf((v.y - mean) * rstd * gg.y + bb.y);
        o4.z = f2bf((v.z - mean) * rstd * gg.z + bb.z);
        o4.w = f2bf((v.w - mean) * rstd * gg.w + bb.w);
        ((ushort4*)(h1 + (size_t)row * D_MODEL))[tid] = o4;
        return;
    }
    // ---- weight transpose ----
    const float* w; unsigned short* wt; int Kd, Nd, bx, by;
    if (id < 4096) {
        int z = id >> 10, t = id & 1023;
        w  = z == 0 ? wq  : z == 1 ? wk  : z == 2 ? wv  : wo;
        wt = z == 0 ? wqt : z == 1 ? wkt : z == 2 ? wvt : wot;
        Kd = 1024; Nd = 1024; bx = t & 31; by = t >> 5;
    } else if (id < 8192) {
        int t = id - 4096;
        w = w1; wt = w1t; Kd = 1024; Nd = 4096; bx = t & 127; by = t >> 7;
    } else {
        int t = id - 8192;
        w = w2; wt = w2t; Kd = 4096; Nd = 1024; bx = t & 31; by = t >> 5;
    }
    int n0 = bx * 32, k0 = by * 32;
    int tx = threadIdx.x & 31, ty = threadIdx.x >> 5;  // 32 x 8
#pragma unroll
    for (int i = 0; i < 4; ++i)
        tile[ty + i * 8][tx] = w[(size_t)(k0 + ty + i * 8) * Nd + n0 + tx];
    __syncthreads();
#pragma unroll
    for (int i = 0; i < 4; ++i)
        wt[(size_t)(n0 + ty + i * 8) * Kd + k0 + tx] = f2bf(tile[tx][ty + i * 8]);
}

// ---------------------------------------------------------------------------
// V transpose: v bf16 [b*1000+s][h*64+dk] -> vt bf16 [b][h*64+dk][1024] (s pad 0)
// ---------------------------------------------------------------------------
__global__ __launch_bounds__(256) void vtrans_kernel(const unsigned short* __restrict__ v,
                                                     unsigned short* __restrict__ vt) {
    __shared__ unsigned short tile[32][33];
    int b = blockIdx.z;
    int c0 = blockIdx.x * 32, s0 = blockIdx.y * 32;
    int tx = threadIdx.x, ty = threadIdx.y;
#pragma unroll
    for (int i = 0; i < 4; ++i) {
        int s = s0 + ty + i * 8;
        unsigned short val = 0;
        if (s < SEQ) val = v[((size_t)b * SEQ + s) * D_MODEL + c0 + tx];
        tile[ty + i * 8][tx] = val;
    }
    __syncthreads();
#pragma unroll
    for (int i = 0; i < 4; ++i) {
        int c = c0 + ty + i * 8;
        vt[((size_t)b * D_MODEL + c) * 1024 + s0 + tx] = tile[tx][ty + i * 8];
    }
}

// ---------------------------------------------------------------------------
// LayerNorm: x fp32 [row][1024] -> out bf16, 1 block per row
// ---------------------------------------------------------------------------
__global__ __launch_bounds__(256) void ln_kernel(const float* __restrict__ x,
                                                 const float* __restrict__ g,
                                                 const float* __restrict__ beta,
                                                 unsigned short* __restrict__ out) {
    int row = blockIdx.x, tid = threadIdx.x;
    const float4 v = ((const float4*)(x + (size_t)row * D_MODEL))[tid];
    float s  = v.x + v.y + v.z + v.w;
    float s2 = v.x * v.x + v.y * v.y + v.z * v.z + v.w * v.w;
#pragma unroll
    for (int o = 32; o > 0; o >>= 1) { s += __shfl_xor(s, o, 64); s2 += __shfl_xor(s2, o, 64); }
    __shared__ float red[8];
    int wave = tid >> 6, lane = tid & 63;
    if (lane == 0) { red[wave] = s; red[wave + 4] = s2; }
    __syncthreads();
    s  = red[0] + red[1] + red[2] + red[3];
    s2 = red[4] + red[5] + red[6] + red[7];
    float mean = s * (1.0f / D_MODEL);
    float var  = s2 * (1.0f / D_MODEL) - mean * mean;
    float rstd = rsqrtf(var + 1e-5f);
    float4 gg = ((const float4*)g)[tid];
    float4 bb = ((const float4*)beta)[tid];
    ushort4 o4;
    o4.x = f2bf((v.x - mean) * rstd * gg.x + bb.x);
    o4.y = f2bf((v.y - mean) * rstd * gg.y + bb.y);
    o4.z = f2bf((v.z - mean) * rstd * gg.z + bb.z);
    o4.w = f2bf((v.w - mean) * rstd * gg.w + bb.w);
    ((ushort4*)(out + (size_t)row * D_MODEL))[tid] = o4;
}

enum { EPI_BF16 = 0, EPI_GELU = 1, EPI_RES_F32 = 2 };

// ---------------------------------------------------------------------------
// gemm128p: 128x256 tile, 8 waves (2M x 4N), per-wave 64x64 (acc[4][4]).
// TWO 32-K tiles per iteration, 6-slot LDS ring (144 KiB), prefetch +4/+5.
//
// Why: R2 counters showed 1631 cyc/tile vs ~620 MFMA / ~790 LDS floors —
// the gap is the per-tile {barrier -> 8 ds_read -> lgkm -> MFMA} serial
// chain with only 2 waves/SIMD. Pairing tiles gives ONE vmcnt+barrier per
// 64-K, and all 16 ds_reads issue up front so tile t+1's reads complete
// under tile t's 16-MFMA cluster (compiler emits fine-grained lgkmcnt).
//
// vmcnt ledger (3 loads/thread/tile, FIFO retirement):
//  - prologue stages tiles 0..3 (12 loads).
//  - pair (t,t+1) head: outstanding = stages for t+2,t+3 (6 loads) ->
//    vmcnt(6) proves t and t+1 landed; never drains mid-loop. Last pair
//    (t+2==NT): vmcnt(0).
//  - during pair: issue stage(t+4)->slot (t+4)%6 == (t-2)%6, whose reads
//    were lgkm-drained (MFMA-consumed) before this pair's head barrier.
//  - in-loop vmem ops are EXACTLY the staging loads (epilogue loads after).
// Staging inverse-swizzle + lane-constant read swizzle identical to the
// R2-proven gemm128 (2-way max bank aliasing, measured 0 conflicts).
// ---------------------------------------------------------------------------
template <int EPI, bool FUSE3>
__global__ __launch_bounds__(512, 2) void gemm128p(
    const unsigned short* __restrict__ A,
    const unsigned short* __restrict__ Bt0,
    const unsigned short* __restrict__ Bt1,
    const unsigned short* __restrict__ Bt2,
    const float* __restrict__ bias,
    const float* __restrict__ resid,
    void* __restrict__ out0, void* out1, void* out2,
    int Mdim, int Ndim, int K) {
    __shared__ unsigned short ldsA[6][128 * 32];   // 8 KB/slot
    __shared__ unsigned short ldsB[6][256 * 32];   // 16 KB/slot -> 144 KiB total
    int tid = threadIdx.x;
    int lane = tid & 63, wave = tid >> 6;
    int l15 = lane & 15, quad = lane >> 4;
    int wr = wave >> 2;        // 0..1 -> rows wr*64..
    int wc = wave & 3;         // 0..3 -> cols wc*64..
    int rt = blockIdx.y * 128;
    const unsigned short* Bt = Bt0;
    void* outp = out0;
    int ct;
    if (FUSE3) {
        int sel = blockIdx.x >> 2;
        ct = (blockIdx.x & 3) * 256;
        Bt   = sel == 0 ? Bt0  : (sel == 1 ? Bt1  : Bt2);
        outp = sel == 0 ? out0 : (sel == 1 ? out1 : out2);
    } else {
        ct = blockIdx.x * 256;
    }

    // staging sources (inverse swizzle on global addr; LDS dest stays linear)
    // A: 512 granules -> 1/thread (gl = tid); B: 1024 granules -> 2/thread
    const unsigned short* aSrc;
    {
        int p = tid >> 3, sp = (tid & 7) ^ (p & 7);
        int rrow = 2 * p + (sp >> 2), g2 = sp & 3;
        int ar = rt + rrow; if (ar >= Mdim) ar = Mdim - 1;
        aSrc = A + (size_t)ar * K + g2 * 8;
    }
    const unsigned short* bSrc[2];
#pragma unroll
    for (int j = 0; j < 2; ++j) {
        int gl = tid + j * 512;
        int p = gl >> 3, sp = (gl & 7) ^ (p & 7);
        int rrow = 2 * p + (sp >> 2), g2 = sp & 3;
        bSrc[j] = Bt + (size_t)(ct + rrow) * K + g2 * 8;
    }
    auto stage = [&](int kt, int sl) {
        gload_lds16(aSrc + (size_t)kt * 32, (char*)ldsA[sl] + wave * 1024);
        gload_lds16(bSrc[0] + (size_t)kt * 32, (char*)ldsB[sl] + wave * 1024);
        gload_lds16(bSrc[1] + (size_t)kt * 32, (char*)ldsB[sl] + 8192 + wave * 1024);
    };

    // fragment read offsets (lane-constant swizzle slot; proven in R2)
    int lh = l15 >> 1;
    int mslot = (quad + ((l15 & 1) << 2)) ^ lh;
    unsigned aOff = (unsigned)((wr * 32 + lh) * 128 + mslot * 16);
    unsigned bOff = (unsigned)((wc * 32 + lh) * 128 + mslot * 16);

    f32x4_t acc[4][4] = {};
    int NT = K >> 5;   // BK=32; NT even, >= 32 at all call sites

    stage(0, 0); stage(1, 1); stage(2, 2); stage(3, 3);

    int s0 = 0;                     // s0 = t % 6, cycles 0,2,4
    for (int t = 0; t < NT; t += 2) {
        int s1 = s0 + 1;                         // (t+1)%6
        int s4 = (s0 >= 2) ? s0 - 2 : s0 + 4;    // (t+4)%6
        int s5 = s4 + 1;                         // (t+5)%6
        if (t + 2 < NT) asm volatile("s_waitcnt vmcnt(6)" ::: "memory");
        else            asm volatile("s_waitcnt vmcnt(0)" ::: "memory");
        __builtin_amdgcn_s_barrier();
        const char* la0 = (const char*)ldsA[s0];
        const char* lb0 = (const char*)ldsB[s0];
        const char* la1 = (const char*)ldsA[s1];
        const char* lb1 = (const char*)ldsB[s1];
        short8_t af0[4], bf0[4], af1[4], bf1[4];
#pragma unroll
        for (int mi = 0; mi < 4; ++mi)
            af0[mi] = *(const short8_t*)(la0 + aOff + mi * 1024);
#pragma unroll
        for (int ni = 0; ni < 4; ++ni)
            bf0[ni] = *(const short8_t*)(lb0 + bOff + ni * 1024);
        if (t + 4 < NT) stage(t + 4, s4);
#pragma unroll
        for (int mi = 0; mi < 4; ++mi)
            af1[mi] = *(const short8_t*)(la1 + aOff + mi * 1024);
#pragma unroll
        for (int ni = 0; ni < 4; ++ni)
            bf1[ni] = *(const short8_t*)(lb1 + bOff + ni * 1024);
        if (t + 5 < NT) stage(t + 5, s5);
        __builtin_amdgcn_s_setprio(1);
#pragma unroll
        for (int mi = 0; mi < 4; ++mi)
#pragma unroll
            for (int ni = 0; ni < 4; ++ni)
                acc[mi][ni] = mfma_bf16(af0[mi], bf0[ni], acc[mi][ni]);
#pragma unroll
        for (int mi = 0; mi < 4; ++mi)
#pragma unroll
            for (int ni = 0; ni < 4; ++ni)
                acc[mi][ni] = mfma_bf16(af1[mi], bf1[ni], acc[mi][ni]);
        __builtin_amdgcn_s_setprio(0);
        s0 += 2; if (s0 >= 6) s0 -= 6;
    }

    float bias_c[4];
    if (EPI != EPI_BF16) {
#pragma unroll
        for (int ni = 0; ni < 4; ++ni) bias_c[ni] = bias[ct + wc * 64 + ni * 16 + l15];
    }

    // epilogue: C/D layout col=lane&15, row=quad*4+reg
#pragma unroll
    for (int mi = 0; mi < 4; ++mi) {
#pragma unroll
        for (int r = 0; r < 4; ++r) {
            int grow = rt + wr * 64 + mi * 16 + quad * 4 + r;
            if (grow >= Mdim) continue;
#pragma unroll
            for (int ni = 0; ni < 4; ++ni) {
                int gcol = ct + wc * 64 + ni * 16 + l15;
                float v = acc[mi][ni][r];
                size_t idx = (size_t)grow * Ndim + gcol;
                if (EPI == EPI_BF16) {
                    ((unsigned short*)outp)[idx] = f2bf(v);
                } else if (EPI == EPI_GELU) {
                    v += bias_c[ni];
                    ((unsigned short*)outp)[idx] = f2bf(gelu_fast(v));
                } else {
                    v += bias_c[ni] + resid[idx];
                    ((float*)outp)[idx] = v;
                }
            }
        }
    }
}

// ---------------------------------------------------------------------------
// Flash attention v3: triangle-balanced + double-buffered DMA staging.
// (unchanged — proven)
// ---------------------------------------------------------------------------
__global__ __launch_bounds__(256) void attn_kernel(
    const unsigned short* __restrict__ q,
    const unsigned short* __restrict__ k,
    const unsigned short* __restrict__ vt,
    unsigned short* __restrict__ att) {
    int p = blockIdx.x, h = blockIdx.y, b = blockIdx.z;
    int tid = threadIdx.x, lane = tid & 63, wave = tid >> 6;
    int l15 = lane & 15, quad = lane >> 4;
    __shared__ unsigned short kt_lds[2][64 * 64];
    __shared__ unsigned short vt_lds[2][64 * 64];
    __shared__ unsigned short p_lds[4][32 * 64];
    unsigned short* pw = p_lds[wave];

    const int qtA = p, qtB = 7 - p;
    const int tA = 2 * qtA + 2, tB = 2 * qtB + 2, total = tA + tB;  // == 18

    short8_t aq[2][2][2];  // [phase][g][kc]
#pragma unroll
    for (int ph = 0; ph < 2; ++ph) {
        int qw = (ph ? qtB : qtA) * 128 + wave * 32;
#pragma unroll
        for (int g = 0; g < 2; ++g) {
            int qr = qw + g * 16 + l15; if (qr > SEQ - 1) qr = SEQ - 1;
            const unsigned short* qp = q + ((size_t)(b * SEQ + qr)) * D_MODEL + h * 64 + quad * 8;
            aq[ph][g][0] = *(const short8_t*)qp;
            aq[ph][g][1] = *(const short8_t*)(qp + 32);
        }
    }

    f32x4_t o[2][4] = {};
    float m_run[2] = {-3.0e38f, -3.0e38f};
    float l_run[2] = {0.f, 0.f};

    auto stage = [&](int kt, int bufi) {
#pragma unroll
        for (int i = 0; i < 2; ++i) {
            int g2 = tid + i * 256;
            int row = g2 >> 3, cp = g2 & 7;
            int c = cp ^ (row & 7);
            int key = kt * 64 + row; int keyc = key < SEQ ? key : SEQ - 1;
            gload_lds16(k + ((size_t)(b * SEQ + keyc)) * D_MODEL + h * 64 + c * 8,
                        (char*)kt_lds[bufi] + (size_t)(wave * 64 + i * 256) * 16);
            gload_lds16(vt + ((size_t)((b * N_HEADS + h) * 64 + row)) * 1024 + kt * 64 + c * 8,
                        (char*)vt_lds[bufi] + (size_t)(wave * 64 + i * 256) * 16);
        }
    };

    auto flush = [&](int qt) {
#pragma unroll
        for (int g = 0; g < 2; ++g) {
            float linv = __builtin_amdgcn_rcpf(l_run[g]);
#pragma unroll
            for (int r = 0; r < 4; ++r) {
                float nr = __shfl(linv, quad * 4 + r, 64);
                int qg = qt * 128 + wave * 32 + g * 16 + quad * 4 + r;
                if (qg >= SEQ) continue;
#pragma unroll
                for (int db = 0; db < 4; ++db)
                    att[((size_t)(b * SEQ + qg)) * D_MODEL + h * 64 + db * 16 + l15] =
                        f2bf(o[g][db][r] * nr);
            }
        }
#pragma unroll
        for (int g = 0; g < 2; ++g) {
            m_run[g] = -3.0e38f; l_run[g] = 0.f;
#pragma unroll
            for (int db = 0; db < 4; ++db) o[g][db] = f32x4_t{0.f, 0.f, 0.f, 0.f};
        }
    };

    stage(0, 0);

    for (int i = 0; i < total; ++i) {
        int bufi = i & 1;
        __syncthreads();
        if (i + 1 < total) {
            int nkt = (i + 1 < tA) ? (i + 1) : (i + 1 - tA);
            stage(nkt, bufi ^ 1);
        }
        int phase = (i < tA) ? 0 : 1;
        int kt = (i < tA) ? i : i - tA;
        int qt = phase ? qtB : qtA;
        int qw = qt * 128 + wave * 32;
        const unsigned short* kl = kt_lds[bufi];
        const unsigned short* vl = vt_lds[bufi];

        if (kt * 64 <= qw + 31) {
            short8_t kf[4][2];
#pragma unroll
            for (int nb = 0; nb < 4; ++nb)
#pragma unroll
                for (int kc = 0; kc < 2; ++kc) {
                    int row = nb * 16 + l15;
                    kf[nb][kc] = *(const short8_t*)(kl + (row * 8 + ((kc * 4 + quad) ^ (row & 7))) * 8);
                }

            bool gact[2];
#pragma unroll
            for (int g = 0; g < 2; ++g) {
                gact[g] = (kt * 64 <= qw + g * 16 + 15);
                if (!gact[g]) continue;
                f32x4_t s[4] = {};
#pragma unroll
                for (int nb = 0; nb < 4; ++nb)
#pragma unroll
                    for (int kc = 0; kc < 2; ++kc)
                        s[nb] = mfma_bf16(kf[nb][kc], aq[phase][g][kc], s[nb]);
                int qrow = qw + g * 16 + l15;
                float sc[4][4];
#pragma unroll
                for (int nb = 0; nb < 4; ++nb)
#pragma unroll
                    for (int r = 0; r < 4; ++r) {
                        int key = kt * 64 + nb * 16 + quad * 4 + r;
                        float v = s[nb][r] * 0.125f;
                        sc[nb][r] = (key <= qrow) ? v : -1e30f;
                    }
                float mx = sc[0][0];
#pragma unroll
                for (int nb = 0; nb < 4; ++nb)
#pragma unroll
                    for (int r = 0; r < 4; ++r) mx = fmaxf(mx, sc[nb][r]);
                mx = fmaxf(mx, __shfl_xor(mx, 16, 64));
                mx = fmaxf(mx, __shfl_xor(mx, 32, 64));
                float mnew = fmaxf(m_run[g], mx);
                float alpha = __expf(m_run[g] - mnew);
                m_run[g] = mnew;
                float rs = 0.f;
#pragma unroll
                for (int nb = 0; nb < 4; ++nb)
#pragma unroll
                    for (int r = 0; r < 4; ++r) {
                        float pv = __expf(sc[nb][r] - mnew);
                        sc[nb][r] = pv;
                        rs += pv;
                    }
                rs += __shfl_xor(rs, 16, 64);
                rs += __shfl_xor(rs, 32, 64);
                l_run[g] = l_run[g] * alpha + rs;
#pragma unroll
                for (int r = 0; r < 4; ++r) {
                    float a = __shfl(alpha, quad * 4 + r, 64);
#pragma unroll
                    for (int db = 0; db < 4; ++db) o[g][db][r] *= a;
                }
#pragma unroll
                for (int nb = 0; nb < 4; ++nb) {
                    unsigned long long pv =
                        (unsigned long long)f2bf(sc[nb][0]) |
                        ((unsigned long long)f2bf(sc[nb][1]) << 16) |
                        ((unsigned long long)f2bf(sc[nb][2]) << 32) |
                        ((unsigned long long)f2bf(sc[nb][3]) << 48);
                    int chunk = (4 * nb + quad) ^ ((l15 & 7) << 1);
                    *(unsigned long long*)(pw + (g * 16 + l15) * 64 + chunk * 4) = pv;
                }
            }
            asm volatile("s_waitcnt lgkmcnt(0)" ::: "memory");

            short8_t vf[4][2];
#pragma unroll
            for (int db = 0; db < 4; ++db)
#pragma unroll
                for (int kc = 0; kc < 2; ++kc) {
                    int row = db * 16 + l15;
                    vf[db][kc] = *(const short8_t*)(vl + (row * 8 + ((kc * 4 + quad) ^ (row & 7))) * 8);
                }
#pragma unroll
            for (int g = 0; g < 2; ++g) {
                if (!gact[g]) continue;
                short8_t ap[2];
#pragma unroll
                for (int kc = 0; kc < 2; ++kc)
                    ap[kc] = *(const short8_t*)(pw + (g * 16 + l15) * 64 +
                                                ((kc * 4 + quad) ^ (l15 & 7)) * 8);
#pragma unroll
                for (int db = 0; db < 4; ++db)
#pragma unroll
                    for (int kc = 0; kc < 2; ++kc)
                        o[g][db] = mfma_bf16(ap[kc], vf[db][kc], o[g][db]);
            }
        }

        if (i == tA - 1) flush(qtA);
    }
    flush(qtB);
}

// ---------------------------------------------------------------------------
extern "C" void kernel_launch(void* const* d_in, const int* in_sizes, int n_in,
                              void* d_out, int out_size, void* d_ws, size_t ws_size,
                              hipStream_t stream) {
    const float* x     = (const float*)d_in[0];
    const float* wq    = (const float*)d_in[1];
    const float* wk    = (const float*)d_in[2];
    const float* wv    = (const float*)d_in[3];
    const float* wo    = (const float*)d_in[4];
    const float* bo    = (const float*)d_in[5];
    const float* w1    = (const float*)d_in[6];
    const float* b1    = (const float*)d_in[7];
    const float* w2    = (const float*)d_in[8];
    const float* b2    = (const float*)d_in[9];
    const float* g1    = (const float*)d_in[10];
    const float* beta1 = (const float*)d_in[11];
    const float* g2    = (const float*)d_in[12];
    const float* beta2 = (const float*)d_in[13];
    float* out = (float*)d_out;
    char* ws = (char*)d_ws;

    const size_t SZ_MD_BF16 = (size_t)M_TOK * D_MODEL * 2;  // 16,384,000
    unsigned short* h1  = (unsigned short*)(ws);                       // also h2 (alias)
    unsigned short* qb  = (unsigned short*)(ws + SZ_MD_BF16);
    unsigned short* kb  = (unsigned short*)(ws + 2 * SZ_MD_BF16);
    unsigned short* vb  = (unsigned short*)(ws + 3 * SZ_MD_BF16);
    unsigned short* atb = (unsigned short*)(ws + 4 * SZ_MD_BF16);
    unsigned short* ffb = qb;                                          // alias: q..att dead after WO
    size_t off = 5 * SZ_MD_BF16;
    unsigned short* vtb = (unsigned short*)(ws + off); off += (size_t)BATCH * D_MODEL * 1024 * 2; // 16.78MB
    float* x1 = (float*)(ws + off); off += (size_t)M_TOK * D_MODEL * 4;
    unsigned short* wqt = (unsigned short*)(ws + off); off += (size_t)D_MODEL * D_MODEL * 2;
    unsigned short* wkt = (unsigned short*)(ws + off); off += (size_t)D_MODEL * D_MODEL * 2;
    unsigned short* wvt = (unsigned short*)(ws + off); off += (size_t)D_MODEL * D_MODEL * 2;
    unsigned short* wot = (unsigned short*)(ws + off); off += (size_t)D_MODEL * D_MODEL * 2;
    unsigned short* w1t = (unsigned short*)(ws + off); off += (size_t)D_MODEL * D_FF * 2;
    unsigned short* w2t = (unsigned short*)(ws + off); off += (size_t)D_MODEL * D_FF * 2;

    // all weight transposes + LN1 in one launch
    prep_kernel<<<12288 + M_TOK, 256, 0, stream>>>(
        wq, wk, wv, wo, w1, w2, wqt, wkt, wvt, wot, w1t, w2t, x, g1, beta1, h1);

    const int MT128 = (M_TOK + 127) / 128;  // 63

    // QKV fused: 12 x 63 = 756 blocks
    gemm128p<EPI_BF16, true><<<dim3(12, MT128), 512, 0, stream>>>(
        h1, wqt, wkt, wvt, nullptr, nullptr, qb, kb, vb, M_TOK, D_MODEL, D_MODEL);

    dim3 tb(32, 8);
    vtrans_kernel<<<dim3(32, 32, 8), tb, 0, stream>>>(vb, vtb);

    attn_kernel<<<dim3(4, N_HEADS, BATCH), 256, 0, stream>>>(qb, kb, vtb, atb);

    // WO: 4 x 63 = 252 blocks
    gemm128p<EPI_RES_F32, false><<<dim3(4, MT128), 512, 0, stream>>>(
        atb, wot, nullptr, nullptr, bo, x, x1, nullptr, nullptr, M_TOK, D_MODEL, D_MODEL);

    ln_kernel<<<M_TOK, 256, 0, stream>>>(x1, g2, beta2, h1);  // h2 aliases h1

    // FFN1: 16 x 63 = 1008 blocks
    gemm128p<EPI_GELU, false><<<dim3(16, MT128), 512, 0, stream>>>(
        h1, w1t, nullptr, nullptr, b1, nullptr, ffb, nullptr, nullptr, M_TOK, D_FF, D_MODEL);

    // FFN2: 4 x 63 = 252 blocks, K=4096 deep pipeline
    gemm128p<EPI_RES_F32, false><<<dim3(4, MT128), 512, 0, stream>>>(
        ffb, w2t, nullptr, nullptr, b2, x1, out, nullptr, nullptr, M_TOK, D_MODEL, D_FF);
}

// Round 4
// 475.937 us; speedup vs baseline: 1.0805x; 1.0805x over previous
//
#include <hip/hip_runtime.h>
#include <hip/hip_bf16.h>
#include <math.h>

#define D_MODEL 1024
#define D_FF    4096
#define N_HEADS 16
#define SEQ     1000
#define BATCH   8
#define M_TOK   (BATCH * SEQ)   // 8000 tokens

typedef __bf16 bf16x8_t __attribute__((ext_vector_type(8)));
typedef short  short8_t __attribute__((ext_vector_type(8)));
typedef float  f32x4_t  __attribute__((ext_vector_type(4)));

__device__ __forceinline__ f32x4_t mfma_bf16(short8_t a, short8_t b, f32x4_t c) {
    return __builtin_amdgcn_mfma_f32_16x16x32_bf16(
        __builtin_bit_cast(bf16x8_t, a), __builtin_bit_cast(bf16x8_t, b), c, 0, 0, 0);
}

// fp32 -> bf16 round-to-nearest-even
__device__ __forceinline__ unsigned short f2bf(float f) {
    union { float f; unsigned u; } x; x.f = f;
    unsigned r = (x.u + 0x7fffu + ((x.u >> 16) & 1u)) >> 16;
    return (unsigned short)r;
}

// fast GELU (tanh form): max abs dev vs exact erf-GELU ~3e-4, below bf16 rounding
__device__ __forceinline__ float gelu_fast(float v) {
    float z = 1.5957691216f * v * fmaf(0.044715f, v * v, 1.0f);
    float e = __expf(-z);                       // v_exp_f32
    return v * __builtin_amdgcn_rcpf(1.0f + e); // v_rcp_f32
}

// async global(16B/lane) -> LDS (wave-uniform base + lane*16)
__device__ __forceinline__ void gload_lds16(const void* g, void* l) {
    __builtin_amdgcn_global_load_lds(
        (const __attribute__((address_space(1))) unsigned int*)g,
        (__attribute__((address_space(3))) unsigned int*)l, 16, 0, 0);
}

// ---------------------------------------------------------------------------
// Prep: all 6 weight transposes (fp32 [K][N] -> bf16 [N][K]) + LN1, one launch.
// ---------------------------------------------------------------------------
__global__ __launch_bounds__(256) void prep_kernel(
    const float* __restrict__ wq, const float* __restrict__ wk,
    const float* __restrict__ wv, const float* __restrict__ wo,
    const float* __restrict__ w1, const float* __restrict__ w2,
    unsigned short* __restrict__ wqt, unsigned short* __restrict__ wkt,
    unsigned short* __restrict__ wvt, unsigned short* __restrict__ wot,
    unsigned short* __restrict__ w1t, unsigned short* __restrict__ w2t,
    const float* __restrict__ x, const float* __restrict__ g1,
    const float* __restrict__ beta1, unsigned short* __restrict__ h1) {
    int id = blockIdx.x;
    __shared__ float tile[32][33];
    __shared__ float red[8];
    if (id >= 12288) {
        // ---- LayerNorm row ----
        int row = id - 12288, tid = threadIdx.x;
        const float4 v = ((const float4*)(x + (size_t)row * D_MODEL))[tid];
        float s  = v.x + v.y + v.z + v.w;
        float s2 = v.x * v.x + v.y * v.y + v.z * v.z + v.w * v.w;
#pragma unroll
        for (int o = 32; o > 0; o >>= 1) { s += __shfl_xor(s, o, 64); s2 += __shfl_xor(s2, o, 64); }
        int wave = tid >> 6, lane = tid & 63;
        if (lane == 0) { red[wave] = s; red[wave + 4] = s2; }
        __syncthreads();
        s  = red[0] + red[1] + red[2] + red[3];
        s2 = red[4] + red[5] + red[6] + red[7];
        float mean = s * (1.0f / D_MODEL);
        float var  = s2 * (1.0f / D_MODEL) - mean * mean;
        float rstd = rsqrtf(var + 1e-5f);
        float4 gg = ((const float4*)g1)[tid];
        float4 bb = ((const float4*)beta1)[tid];
        ushort4 o4;
        o4.x = f2bf((v.x - mean) * rstd * gg.x + bb.x);
        o4.y = f2bf((v.y - mean) * rstd * gg.y + bb.y);
        o4.z = f2bf((v.z - mean) * rstd * gg.z + bb.z);
        o4.w = f2bf((v.w - mean) * rstd * gg.w + bb.w);
        ((ushort4*)(h1 + (size_t)row * D_MODEL))[tid] = o4;
        return;
    }
    // ---- weight transpose ----
    const float* w; unsigned short* wt; int Kd, Nd, bx, by;
    if (id < 4096) {
        int z = id >> 10, t = id & 1023;
        w  = z == 0 ? wq  : z == 1 ? wk  : z == 2 ? wv  : wo;
        wt = z == 0 ? wqt : z == 1 ? wkt : z == 2 ? wvt : wot;
        Kd = 1024; Nd = 1024; bx = t & 31; by = t >> 5;
    } else if (id < 8192) {
        int t = id - 4096;
        w = w1; wt = w1t; Kd = 1024; Nd = 4096; bx = t & 127; by = t >> 7;
    } else {
        int t = id - 8192;
        w = w2; wt = w2t; Kd = 4096; Nd = 1024; bx = t & 31; by = t >> 5;
    }
    int n0 = bx * 32, k0 = by * 32;
    int tx = threadIdx.x & 31, ty = threadIdx.x >> 5;  // 32 x 8
#pragma unroll
    for (int i = 0; i < 4; ++i)
        tile[ty + i * 8][tx] = w[(size_t)(k0 + ty + i * 8) * Nd + n0 + tx];
    __syncthreads();
#pragma unroll
    for (int i = 0; i < 4; ++i)
        wt[(size_t)(n0 + ty + i * 8) * Kd + k0 + tx] = f2bf(tile[tx][ty + i * 8]);
}

// ---------------------------------------------------------------------------
// V transpose: v bf16 [b*1000+s][h*64+dk] -> vt bf16 [b][h*64+dk][1024] (s pad 0)
// ---------------------------------------------------------------------------
__global__ __launch_bounds__(256) void vtrans_kernel(const unsigned short* __restrict__ v,
                                                     unsigned short* __restrict__ vt) {
    __shared__ unsigned short tile[32][33];
    int b = blockIdx.z;
    int c0 = blockIdx.x * 32, s0 = blockIdx.y * 32;
    int tx = threadIdx.x, ty = threadIdx.y;
#pragma unroll
    for (int i = 0; i < 4; ++i) {
        int s = s0 + ty + i * 8;
        unsigned short val = 0;
        if (s < SEQ) val = v[((size_t)b * SEQ + s) * D_MODEL + c0 + tx];
        tile[ty + i * 8][tx] = val;
    }
    __syncthreads();
#pragma unroll
    for (int i = 0; i < 4; ++i) {
        int c = c0 + ty + i * 8;
        vt[((size_t)b * D_MODEL + c) * 1024 + s0 + tx] = tile[tx][ty + i * 8];
    }
}

// ---------------------------------------------------------------------------
// LayerNorm: x fp32 [row][1024] -> out bf16, 1 block per row
// ---------------------------------------------------------------------------
__global__ __launch_bounds__(256) void ln_kernel(const float* __restrict__ x,
                                                 const float* __restrict__ g,
                                                 const float* __restrict__ beta,
                                                 unsigned short* __restrict__ out) {
    int row = blockIdx.x, tid = threadIdx.x;
    const float4 v = ((const float4*)(x + (size_t)row * D_MODEL))[tid];
    float s  = v.x + v.y + v.z + v.w;
    float s2 = v.x * v.x + v.y * v.y + v.z * v.z + v.w * v.w;
#pragma unroll
    for (int o = 32; o > 0; o >>= 1) { s += __shfl_xor(s, o, 64); s2 += __shfl_xor(s2, o, 64); }
    __shared__ float red[8];
    int wave = tid >> 6, lane = tid & 63;
    if (lane == 0) { red[wave] = s; red[wave + 4] = s2; }
    __syncthreads();
    s  = red[0] + red[1] + red[2] + red[3];
    s2 = red[4] + red[5] + red[6] + red[7];
    float mean = s * (1.0f / D_MODEL);
    float var  = s2 * (1.0f / D_MODEL) - mean * mean;
    float rstd = rsqrtf(var + 1e-5f);
    float4 gg = ((const float4*)g)[tid];
    float4 bb = ((const float4*)beta)[tid];
    ushort4 o4;
    o4.x = f2bf((v.x - mean) * rstd * gg.x + bb.x);
    o4.y = f2bf((v.y - mean) * rstd * gg.y + bb.y);
    o4.z = f2bf((v.z - mean) * rstd * gg.z + bb.z);
    o4.w = f2bf((v.w - mean) * rstd * gg.w + bb.w);
    ((ushort4*)(out + (size_t)row * D_MODEL))[tid] = o4;
}

enum { EPI_BF16 = 0, EPI_GELU = 1, EPI_RES_F32 = 2 };

// ---------------------------------------------------------------------------
// gemm128t: 128x256 tile, 8 waves (2M x 4N), per-wave 64x64 (acc[4][4]),
// BK=32, SLOTS-deep LDS ring, prefetch distance SLOTS-1, counted vmcnt.
//
// SLOTS=4 (96 KiB, 1 block/CU, launch_bounds(512,2)): byte-identical to the
//   R2-proven gemm128 (87 us FFN2, 0 bank conflicts). Used for WO/FFN2
//   (252 blocks -- can't co-residence 2 blocks/CU anyway).
// SLOTS=3 (72 KiB -> 2 blocks/CU, launch_bounds(512,4)): R4 experiment.
//   R2/R3 showed every structure at ~half its pipe ceiling at 1 block/CU
//   (2 waves/SIMD): sync/latency exposure, not pipe saturation. 2 blocks/CU
//   doubles TLP so one block's MFMA covers the other's vmcnt/barrier stalls
//   (m97-style implicit overlap). Used for QKV (756 blocks) and FFN1 (1008).
//
// vmcnt ledger (3 loads/thread/tile, FIFO):
//   SLOTS=4: head of t needs tiles<=t landed; staged through t+2 -> outstanding
//     6 -> vmcnt(6); rem==1 -> 3; rem==0 -> 0.   (R2-proven)
//   SLOTS=3: staged through t+1 -> outstanding 3 -> vmcnt(3); rem==0 -> 0.
//   stage(t+DIST) targets slot (t-1)%SLOTS whose ds_reads were lgkm-consumed
//   before this iteration's head barrier -> write-after-read safe.
// ---------------------------------------------------------------------------
template <int EPI, bool FUSE3, int SLOTS>
__global__ __launch_bounds__(512, SLOTS == 3 ? 4 : 2) void gemm128t(
    const unsigned short* __restrict__ A,
    const unsigned short* __restrict__ Bt0,
    const unsigned short* __restrict__ Bt1,
    const unsigned short* __restrict__ Bt2,
    const float* __restrict__ bias,
    const float* __restrict__ resid,
    void* __restrict__ out0, void* out1, void* out2,
    int Mdim, int Ndim, int K) {
    constexpr int DIST = SLOTS - 1;
    __shared__ unsigned short ldsA[SLOTS][128 * 32];   // 8 KB/slot
    __shared__ unsigned short ldsB[SLOTS][256 * 32];   // 16 KB/slot
    int tid = threadIdx.x;
    int lane = tid & 63, wave = tid >> 6;
    int l15 = lane & 15, quad = lane >> 4;
    int wr = wave >> 2;        // 0..1 -> rows wr*64..
    int wc = wave & 3;         // 0..3 -> cols wc*64..
    int rt = blockIdx.y * 128;
    const unsigned short* Bt = Bt0;
    void* outp = out0;
    int ct;
    if (FUSE3) {
        int sel = blockIdx.x >> 2;
        ct = (blockIdx.x & 3) * 256;
        Bt   = sel == 0 ? Bt0  : (sel == 1 ? Bt1  : Bt2);
        outp = sel == 0 ? out0 : (sel == 1 ? out1 : out2);
    } else {
        ct = blockIdx.x * 256;
    }

    // staging sources (inverse swizzle on global addr; LDS dest stays linear)
    // A: 512 granules -> 1/thread (gl = tid); B: 1024 granules -> 2/thread
    const unsigned short* aSrc;
    {
        int p = tid >> 3, sp = (tid & 7) ^ (p & 7);
        int rrow = 2 * p + (sp >> 2), g2 = sp & 3;
        int ar = rt + rrow; if (ar >= Mdim) ar = Mdim - 1;
        aSrc = A + (size_t)ar * K + g2 * 8;
    }
    const unsigned short* bSrc[2];
#pragma unroll
    for (int j = 0; j < 2; ++j) {
        int gl = tid + j * 512;
        int p = gl >> 3, sp = (gl & 7) ^ (p & 7);
        int rrow = 2 * p + (sp >> 2), g2 = sp & 3;
        bSrc[j] = Bt + (size_t)(ct + rrow) * K + g2 * 8;
    }
    auto stage = [&](int kt, int sl) {
        gload_lds16(aSrc + (size_t)kt * 32, (char*)ldsA[sl] + wave * 1024);
        gload_lds16(bSrc[0] + (size_t)kt * 32, (char*)ldsB[sl] + wave * 1024);
        gload_lds16(bSrc[1] + (size_t)kt * 32, (char*)ldsB[sl] + 8192 + wave * 1024);
    };

    // fragment read offsets (lane-constant swizzle slot; proven 0-conflict)
    int lh = l15 >> 1;
    int mslot = (quad + ((l15 & 1) << 2)) ^ lh;
    unsigned aOff = (unsigned)((wr * 32 + lh) * 128 + mslot * 16);
    unsigned bOff = (unsigned)((wc * 32 + lh) * 128 + mslot * 16);

    f32x4_t acc[4][4] = {};
    int NT = K >> 5;   // BK=32; all call sites have NT >= 32

#pragma unroll
    for (int d = 0; d < DIST; ++d) stage(d, d);

    int scur = 0, spre = DIST;      // spre = (t+DIST) % SLOTS
    for (int t = 0; t < NT; ++t) {
        int rem = NT - 1 - t;
        if constexpr (SLOTS == 4) {
            if (rem >= 2)      asm volatile("s_waitcnt vmcnt(6)" ::: "memory");
            else if (rem == 1) asm volatile("s_waitcnt vmcnt(3)" ::: "memory");
            else               asm volatile("s_waitcnt vmcnt(0)" ::: "memory");
        } else {
            if (rem >= 1)      asm volatile("s_waitcnt vmcnt(3)" ::: "memory");
            else               asm volatile("s_waitcnt vmcnt(0)" ::: "memory");
        }
        __builtin_amdgcn_s_barrier();
        const char* la = (const char*)ldsA[scur];
        const char* lb = (const char*)ldsB[scur];
        short8_t af[4], bfv[4];
#pragma unroll
        for (int mi = 0; mi < 4; ++mi)
            af[mi] = *(const short8_t*)(la + aOff + mi * 1024);
#pragma unroll
        for (int ni = 0; ni < 4; ++ni)
            bfv[ni] = *(const short8_t*)(lb + bOff + ni * 1024);
        if (t + DIST < NT) stage(t + DIST, spre);
        __builtin_amdgcn_s_setprio(1);
#pragma unroll
        for (int mi = 0; mi < 4; ++mi)
#pragma unroll
            for (int ni = 0; ni < 4; ++ni)
                acc[mi][ni] = mfma_bf16(af[mi], bfv[ni], acc[mi][ni]);
        __builtin_amdgcn_s_setprio(0);
        scur = (scur == SLOTS - 1) ? 0 : scur + 1;
        spre = (spre == SLOTS - 1) ? 0 : spre + 1;
    }

    float bias_c[4];
    if (EPI != EPI_BF16) {
#pragma unroll
        for (int ni = 0; ni < 4; ++ni) bias_c[ni] = bias[ct + wc * 64 + ni * 16 + l15];
    }

    // epilogue: C/D layout col=lane&15, row=quad*4+reg
#pragma unroll
    for (int mi = 0; mi < 4; ++mi) {
#pragma unroll
        for (int r = 0; r < 4; ++r) {
            int grow = rt + wr * 64 + mi * 16 + quad * 4 + r;
            if (grow >= Mdim) continue;
#pragma unroll
            for (int ni = 0; ni < 4; ++ni) {
                int gcol = ct + wc * 64 + ni * 16 + l15;
                float v = acc[mi][ni][r];
                size_t idx = (size_t)grow * Ndim + gcol;
                if (EPI == EPI_BF16) {
                    ((unsigned short*)outp)[idx] = f2bf(v);
                } else if (EPI == EPI_GELU) {
                    v += bias_c[ni];
                    ((unsigned short*)outp)[idx] = f2bf(gelu_fast(v));
                } else {
                    v += bias_c[ni] + resid[idx];
                    ((float*)outp)[idx] = v;
                }
            }
        }
    }
}

// ---------------------------------------------------------------------------
// Flash attention v3: triangle-balanced + double-buffered DMA staging.
// (unchanged — proven)
// ---------------------------------------------------------------------------
__global__ __launch_bounds__(256) void attn_kernel(
    const unsigned short* __restrict__ q,
    const unsigned short* __restrict__ k,
    const unsigned short* __restrict__ vt,
    unsigned short* __restrict__ att) {
    int p = blockIdx.x, h = blockIdx.y, b = blockIdx.z;
    int tid = threadIdx.x, lane = tid & 63, wave = tid >> 6;
    int l15 = lane & 15, quad = lane >> 4;
    __shared__ unsigned short kt_lds[2][64 * 64];
    __shared__ unsigned short vt_lds[2][64 * 64];
    __shared__ unsigned short p_lds[4][32 * 64];
    unsigned short* pw = p_lds[wave];

    const int qtA = p, qtB = 7 - p;
    const int tA = 2 * qtA + 2, tB = 2 * qtB + 2, total = tA + tB;  // == 18

    short8_t aq[2][2][2];  // [phase][g][kc]
#pragma unroll
    for (int ph = 0; ph < 2; ++ph) {
        int qw = (ph ? qtB : qtA) * 128 + wave * 32;
#pragma unroll
        for (int g = 0; g < 2; ++g) {
            int qr = qw + g * 16 + l15; if (qr > SEQ - 1) qr = SEQ - 1;
            const unsigned short* qp = q + ((size_t)(b * SEQ + qr)) * D_MODEL + h * 64 + quad * 8;
            aq[ph][g][0] = *(const short8_t*)qp;
            aq[ph][g][1] = *(const short8_t*)(qp + 32);
        }
    }

    f32x4_t o[2][4] = {};
    float m_run[2] = {-3.0e38f, -3.0e38f};
    float l_run[2] = {0.f, 0.f};

    auto stage = [&](int kt, int bufi) {
#pragma unroll
        for (int i = 0; i < 2; ++i) {
            int g2 = tid + i * 256;
            int row = g2 >> 3, cp = g2 & 7;
            int c = cp ^ (row & 7);
            int key = kt * 64 + row; int keyc = key < SEQ ? key : SEQ - 1;
            gload_lds16(k + ((size_t)(b * SEQ + keyc)) * D_MODEL + h * 64 + c * 8,
                        (char*)kt_lds[bufi] + (size_t)(wave * 64 + i * 256) * 16);
            gload_lds16(vt + ((size_t)((b * N_HEADS + h) * 64 + row)) * 1024 + kt * 64 + c * 8,
                        (char*)vt_lds[bufi] + (size_t)(wave * 64 + i * 256) * 16);
        }
    };

    auto flush = [&](int qt) {
#pragma unroll
        for (int g = 0; g < 2; ++g) {
            float linv = __builtin_amdgcn_rcpf(l_run[g]);
#pragma unroll
            for (int r = 0; r < 4; ++r) {
                float nr = __shfl(linv, quad * 4 + r, 64);
                int qg = qt * 128 + wave * 32 + g * 16 + quad * 4 + r;
                if (qg >= SEQ) continue;
#pragma unroll
                for (int db = 0; db < 4; ++db)
                    att[((size_t)(b * SEQ + qg)) * D_MODEL + h * 64 + db * 16 + l15] =
                        f2bf(o[g][db][r] * nr);
            }
        }
#pragma unroll
        for (int g = 0; g < 2; ++g) {
            m_run[g] = -3.0e38f; l_run[g] = 0.f;
#pragma unroll
            for (int db = 0; db < 4; ++db) o[g][db] = f32x4_t{0.f, 0.f, 0.f, 0.f};
        }
    };

    stage(0, 0);

    for (int i = 0; i < total; ++i) {
        int bufi = i & 1;
        __syncthreads();
        if (i + 1 < total) {
            int nkt = (i + 1 < tA) ? (i + 1) : (i + 1 - tA);
            stage(nkt, bufi ^ 1);
        }
        int phase = (i < tA) ? 0 : 1;
        int kt = (i < tA) ? i : i - tA;
        int qt = phase ? qtB : qtA;
        int qw = qt * 128 + wave * 32;
        const unsigned short* kl = kt_lds[bufi];
        const unsigned short* vl = vt_lds[bufi];

        if (kt * 64 <= qw + 31) {
            short8_t kf[4][2];
#pragma unroll
            for (int nb = 0; nb < 4; ++nb)
#pragma unroll
                for (int kc = 0; kc < 2; ++kc) {
                    int row = nb * 16 + l15;
                    kf[nb][kc] = *(const short8_t*)(kl + (row * 8 + ((kc * 4 + quad) ^ (row & 7))) * 8);
                }

            bool gact[2];
#pragma unroll
            for (int g = 0; g < 2; ++g) {
                gact[g] = (kt * 64 <= qw + g * 16 + 15);
                if (!gact[g]) continue;
                f32x4_t s[4] = {};
#pragma unroll
                for (int nb = 0; nb < 4; ++nb)
#pragma unroll
                    for (int kc = 0; kc < 2; ++kc)
                        s[nb] = mfma_bf16(kf[nb][kc], aq[phase][g][kc], s[nb]);
                int qrow = qw + g * 16 + l15;
                float sc[4][4];
#pragma unroll
                for (int nb = 0; nb < 4; ++nb)
#pragma unroll
                    for (int r = 0; r < 4; ++r) {
                        int key = kt * 64 + nb * 16 + quad * 4 + r;
                        float v = s[nb][r] * 0.125f;
                        sc[nb][r] = (key <= qrow) ? v : -1e30f;
                    }
                float mx = sc[0][0];
#pragma unroll
                for (int nb = 0; nb < 4; ++nb)
#pragma unroll
                    for (int r = 0; r < 4; ++r) mx = fmaxf(mx, sc[nb][r]);
                mx = fmaxf(mx, __shfl_xor(mx, 16, 64));
                mx = fmaxf(mx, __shfl_xor(mx, 32, 64));
                float mnew = fmaxf(m_run[g], mx);
                float alpha = __expf(m_run[g] - mnew);
                m_run[g] = mnew;
                float rs = 0.f;
#pragma unroll
                for (int nb = 0; nb < 4; ++nb)
#pragma unroll
                    for (int r = 0; r < 4; ++r) {
                        float pv = __expf(sc[nb][r] - mnew);
                        sc[nb][r] = pv;
                        rs += pv;
                    }
                rs += __shfl_xor(rs, 16, 64);
                rs += __shfl_xor(rs, 32, 64);
                l_run[g] = l_run[g] * alpha + rs;
#pragma unroll
                for (int r = 0; r < 4; ++r) {
                    float a = __shfl(alpha, quad * 4 + r, 64);
#pragma unroll
                    for (int db = 0; db < 4; ++db) o[g][db][r] *= a;
                }
#pragma unroll
                for (int nb = 0; nb < 4; ++nb) {
                    unsigned long long pv =
                        (unsigned long long)f2bf(sc[nb][0]) |
                        ((unsigned long long)f2bf(sc[nb][1]) << 16) |
                        ((unsigned long long)f2bf(sc[nb][2]) << 32) |
                        ((unsigned long long)f2bf(sc[nb][3]) << 48);
                    int chunk = (4 * nb + quad) ^ ((l15 & 7) << 1);
                    *(unsigned long long*)(pw + (g * 16 + l15) * 64 + chunk * 4) = pv;
                }
            }
            asm volatile("s_waitcnt lgkmcnt(0)" ::: "memory");

            short8_t vf[4][2];
#pragma unroll
            for (int db = 0; db < 4; ++db)
#pragma unroll
                for (int kc = 0; kc < 2; ++kc) {
                    int row = db * 16 + l15;
                    vf[db][kc] = *(const short8_t*)(vl + (row * 8 + ((kc * 4 + quad) ^ (row & 7))) * 8);
                }
#pragma unroll
            for (int g = 0; g < 2; ++g) {
                if (!gact[g]) continue;
                short8_t ap[2];
#pragma unroll
                for (int kc = 0; kc < 2; ++kc)
                    ap[kc] = *(const short8_t*)(pw + (g * 16 + l15) * 64 +
                                                ((kc * 4 + quad) ^ (l15 & 7)) * 8);
#pragma unroll
                for (int db = 0; db < 4; ++db)
#pragma unroll
                    for (int kc = 0; kc < 2; ++kc)
                        o[g][db] = mfma_bf16(ap[kc], vf[db][kc], o[g][db]);
            }
        }

        if (i == tA - 1) flush(qtA);
    }
    flush(qtB);
}

// ---------------------------------------------------------------------------
extern "C" void kernel_launch(void* const* d_in, const int* in_sizes, int n_in,
                              void* d_out, int out_size, void* d_ws, size_t ws_size,
                              hipStream_t stream) {
    const float* x     = (const float*)d_in[0];
    const float* wq    = (const float*)d_in[1];
    const float* wk    = (const float*)d_in[2];
    const float* wv    = (const float*)d_in[3];
    const float* wo    = (const float*)d_in[4];
    const float* bo    = (const float*)d_in[5];
    const float* w1    = (const float*)d_in[6];
    const float* b1    = (const float*)d_in[7];
    const float* w2    = (const float*)d_in[8];
    const float* b2    = (const float*)d_in[9];
    const float* g1    = (const float*)d_in[10];
    const float* beta1 = (const float*)d_in[11];
    const float* g2    = (const float*)d_in[12];
    const float* beta2 = (const float*)d_in[13];
    float* out = (float*)d_out;
    char* ws = (char*)d_ws;

    const size_t SZ_MD_BF16 = (size_t)M_TOK * D_MODEL * 2;  // 16,384,000
    unsigned short* h1  = (unsigned short*)(ws);                       // also h2 (alias)
    unsigned short* qb  = (unsigned short*)(ws + SZ_MD_BF16);
    unsigned short* kb  = (unsigned short*)(ws + 2 * SZ_MD_BF16);
    unsigned short* vb  = (unsigned short*)(ws + 3 * SZ_MD_BF16);
    unsigned short* atb = (unsigned short*)(ws + 4 * SZ_MD_BF16);
    unsigned short* ffb = qb;                                          // alias: q..att dead after WO
    size_t off = 5 * SZ_MD_BF16;
    unsigned short* vtb = (unsigned short*)(ws + off); off += (size_t)BATCH * D_MODEL * 1024 * 2; // 16.78MB
    float* x1 = (float*)(ws + off); off += (size_t)M_TOK * D_MODEL * 4;
    unsigned short* wqt = (unsigned short*)(ws + off); off += (size_t)D_MODEL * D_MODEL * 2;
    unsigned short* wkt = (unsigned short*)(ws + off); off += (size_t)D_MODEL * D_MODEL * 2;
    unsigned short* wvt = (unsigned short*)(ws + off); off += (size_t)D_MODEL * D_MODEL * 2;
    unsigned short* wot = (unsigned short*)(ws + off); off += (size_t)D_MODEL * D_MODEL * 2;
    unsigned short* w1t = (unsigned short*)(ws + off); off += (size_t)D_MODEL * D_FF * 2;
    unsigned short* w2t = (unsigned short*)(ws + off); off += (size_t)D_MODEL * D_FF * 2;

    // all weight transposes + LN1 in one launch
    prep_kernel<<<12288 + M_TOK, 256, 0, stream>>>(
        wq, wk, wv, wo, w1, w2, wqt, wkt, wvt, wot, w1t, w2t, x, g1, beta1, h1);

    const int MT128 = (M_TOK + 127) / 128;  // 63

    // QKV fused: 12 x 63 = 756 blocks, SLOTS=3 -> 2 blocks/CU
    gemm128t<EPI_BF16, true, 3><<<dim3(12, MT128), 512, 0, stream>>>(
        h1, wqt, wkt, wvt, nullptr, nullptr, qb, kb, vb, M_TOK, D_MODEL, D_MODEL);

    dim3 tb(32, 8);
    vtrans_kernel<<<dim3(32, 32, 8), tb, 0, stream>>>(vb, vtb);

    attn_kernel<<<dim3(4, N_HEADS, BATCH), 256, 0, stream>>>(qb, kb, vtb, atb);

    // WO: 4 x 63 = 252 blocks, SLOTS=4 (R2-proven path; can't double up)
    gemm128t<EPI_RES_F32, false, 4><<<dim3(4, MT128), 512, 0, stream>>>(
        atb, wot, nullptr, nullptr, bo, x, x1, nullptr, nullptr, M_TOK, D_MODEL, D_MODEL);

    ln_kernel<<<M_TOK, 256, 0, stream>>>(x1, g2, beta2, h1);  // h2 aliases h1

    // FFN1: 16 x 63 = 1008 blocks, SLOTS=3 -> 2 blocks/CU
    gemm128t<EPI_GELU, false, 3><<<dim3(16, MT128), 512, 0, stream>>>(
        h1, w1t, nullptr, nullptr, b1, nullptr, ffb, nullptr, nullptr, M_TOK, D_FF, D_MODEL);

    // FFN2: 4 x 63 = 252 blocks, SLOTS=4 (R2-proven path)
    gemm128t<EPI_RES_F32, false, 4><<<dim3(4, MT128), 512, 0, stream>>>(
        ffb, w2t, nullptr, nullptr, b2, x1, out, nullptr, nullptr, M_TOK, D_MODEL, D_FF);
}